// Round 1
// 418.777 us; speedup vs baseline: 1.0613x; 1.0613x over previous
//
#include <hip/hip_runtime.h>

typedef __attribute__((ext_vector_type(4))) float f32x4;
typedef __attribute__((ext_vector_type(8))) short s16x8;

#define MFMA16(a, b, c) __builtin_amdgcn_mfma_f32_16x16x32_bf16((a), (b), (c), 0, 0, 0)

// round-to-nearest-even fp32 -> bf16 bits
__device__ __forceinline__ unsigned short f2bf_bits(float f) {
  unsigned int u = __float_as_uint(f);
  unsigned int r = (u + 0x7fffu + ((u >> 16) & 1u)) >> 16;
  return (unsigned short)r;
}

__device__ __forceinline__ void gl_lds16(const void* g, void* l) {
  __builtin_amdgcn_global_load_lds((const __attribute__((address_space(1))) void*)g,
                                   (__attribute__((address_space(3))) void*)l, 16, 0, 0);
}

// fp32 -> bf16 bulk convert, 4 elems/thread
__global__ __launch_bounds__(256) void f2bf_kernel(const float* __restrict__ in,
                                                   unsigned short* __restrict__ out, int n4) {
  int idx = blockIdx.x * 256 + threadIdx.x;
  int stride = gridDim.x * 256;
  for (int i = idx; i < n4; i += stride) {
    float4 v = ((const float4*)in)[i];
    ushort4 o;
    o.x = f2bf_bits(v.x); o.y = f2bf_bits(v.y);
    o.z = f2bf_bits(v.z); o.w = f2bf_bits(v.w);
    ((ushort4*)out)[i] = o;
  }
}

// convert the 4 [1024,1024] weights in one launch; blockIdx.y selects tensor
__global__ __launch_bounds__(256) void f2bf_w4(const float* __restrict__ w0,
                                               const float* __restrict__ w1,
                                               const float* __restrict__ w2,
                                               const float* __restrict__ w3,
                                               unsigned short* __restrict__ o0,
                                               unsigned short* __restrict__ o1,
                                               unsigned short* __restrict__ o2,
                                               unsigned short* __restrict__ o3) {
  const int s = blockIdx.y;
  const float* in = (s == 0) ? w0 : (s == 1) ? w1 : (s == 2) ? w2 : w3;
  unsigned short* out = (s == 0) ? o0 : (s == 1) ? o1 : (s == 2) ? o2 : o3;
  int i = blockIdx.x * 256 + threadIdx.x;  // 1024 blocks x 256 thr x 4 elems = 1M
  float4 v = ((const float4*)in)[i];
  ushort4 o;
  o.x = f2bf_bits(v.x); o.y = f2bf_bits(v.y);
  o.z = f2bf_bits(v.z); o.w = f2bf_bits(v.w);
  ((ushort4*)out)[i] = o;
}

// ============ 256x256-tile, BK=64, 8-wave, 8-phase counted-vmcnt GEMM core ============
// LDS: [2 dbuf][2 half(128 rows)] x 64 cols bf16 for A and B = 128 KiB total.
// Chunk swizzle: logical chunk c (8 bf16 = 16B) of row r stored at position c ^ (r&7).
// Stage is linear global_load_lds (dest = base + lane*16B); the swizzle is applied on the
// per-lane GLOBAL source address (rule: both-sides-or-neither).
// Read side: 16 lanes (l15) hit 8 chunk positions x2 = 2-way bank alias = free (measured 0 conflicts).

#define S_BARRIER asm volatile("s_barrier" ::: "memory")
#define WAIT_LGKM0 asm volatile("s_waitcnt lgkmcnt(0)" ::: "memory")
#define SCHED_FENCE __builtin_amdgcn_sched_barrier(0)

// stage one 128x64 half-tile: 2 x global_load_lds(16B) per thread, 512 threads
#define STAGE_HALF(gsrc, ldst)                                                   \
  {                                                                              \
    _Pragma("unroll") for (int i_ = 0; i_ < 2; ++i_) {                           \
      const int ci_ = tid + 512 * i_;                                            \
      const int r_ = ci_ >> 3;                                                   \
      const int c_ = (ci_ & 7) ^ (r_ & 7);                                       \
      gl_lds16((gsrc) + (size_t)r_ * 1024 + c_ * 8, (ldst) + ci_ * 8);           \
    }                                                                            \
  }

#define LDA8(dst, mf_, ks_)                                                      \
  dst = *(const s16x8*)&Ahalf[(((mf_) * 16 + l15) * 8 +                          \
                               (((ks_) * 4 + quad) ^ (l15 & 7))) * 8]
#define LDB8(dst, nf_, ks_)                                                      \
  dst = *(const s16x8*)&Bhalf[((bro + (nf_) * 16 + l15) * 8 +                    \
                               (((ks_) * 4 + quad) ^ (l15 & 7))) * 8]

// one C-quadrant: 4 m-frags x 2 n-frags x 2 k-slices = 16 MFMA
#define MF_BLOCK(MBASE, NBASE)                                                   \
  _Pragma("unroll") for (int m_ = 0; m_ < 4; ++m_)                               \
    _Pragma("unroll") for (int n_ = 0; n_ < 2; ++n_) {                           \
      acc[(MBASE) + m_][(NBASE) + n_] =                                          \
          MFMA16(af[m_][0], bf[(NBASE) + n_][0], acc[(MBASE) + m_][(NBASE) + n_]); \
      acc[(MBASE) + m_][(NBASE) + n_] =                                          \
          MFMA16(af[m_][1], bf[(NBASE) + n_][1], acc[(MBASE) + m_][(NBASE) + n_]); \
    }

// Stage schedule per tile T: P1: A0(T+1)->obuf, P2: A1(T+1)->obuf,
//                            P3: B0(T+2)->buf,  P4: B1(T+2)->buf.
// All 4 halves of tile T+1 are consumed at P1(T+1), so the once-per-tile wait at P4(T)
// must be vmcnt(4): leaves only P3/P4(T)'s B(T+2) stages (2 stages = 4 loads) in flight.
// Slot-free proof: A slots of obuf last read P3(T-1); B slots of buf last read P2(T);
// each stage is >=1 barrier after the slot's last read.
#define GEMM256_CORE(Ab_, Bb_)                                                   \
  f32x4 acc[8][4];                                                               \
  _Pragma("unroll") for (int mi = 0; mi < 8; ++mi)                               \
      _Pragma("unroll") for (int ni = 0; ni < 4; ++ni)                           \
          acc[mi][ni] = (f32x4){0.f, 0.f, 0.f, 0.f};                             \
  {                                                                              \
    s16x8 af[4][2], bf[4][2];                                                    \
    /* prologue: tile0 (4 halves) -> buf0, tile1 B halves -> buf1 */             \
    STAGE_HALF((Ab_), &Al[0][0][0]);                                             \
    STAGE_HALF((Ab_) + 128 * 1024, &Al[0][1][0]);                                \
    STAGE_HALF((Bb_), &Bl[0][0][0]);                                             \
    STAGE_HALF((Bb_) + 128 * 1024, &Bl[0][1][0]);                                \
    STAGE_HALF((Bb_) + 64, &Bl[1][0][0]);                                        \
    STAGE_HALF((Bb_) + 128 * 1024 + 64, &Bl[1][1][0]);                           \
    asm volatile("s_waitcnt vmcnt(4)" ::: "memory"); /* tile0 complete */        \
    S_BARRIER;                                                                   \
    _Pragma("unroll 2") for (int T = 0; T < 16; ++T) {                           \
      const int buf_ = T & 1, obuf_ = buf_ ^ 1;                                  \
      const unsigned short* Ahalf = &Al[buf_][wm][0];                            \
      const unsigned short* Bhalf = &Bl[buf_][wn >> 1][0];                       \
      /* ---- phase 1: read A mf0-3, B nf0-1; stage A0(T+1); MFMA Q(lo,lo) */    \
      _Pragma("unroll") for (int m_ = 0; m_ < 4; ++m_) {                         \
        LDA8(af[m_][0], m_, 0); LDA8(af[m_][1], m_, 1);                          \
      }                                                                          \
      _Pragma("unroll") for (int n_ = 0; n_ < 2; ++n_) {                         \
        LDB8(bf[n_][0], n_, 0); LDB8(bf[n_][1], n_, 1);                          \
      }                                                                          \
      if (T < 15) STAGE_HALF((Ab_) + (size_t)(T + 1) * 64, &Al[obuf_][0][0]);    \
      S_BARRIER; WAIT_LGKM0; SCHED_FENCE;                                        \
      __builtin_amdgcn_s_setprio(1);                                             \
      MF_BLOCK(0, 0)                                                             \
      __builtin_amdgcn_s_setprio(0);                                             \
      S_BARRIER;                                                                 \
      /* ---- phase 2: read B nf2-3; stage A1(T+1); MFMA Q(lo,hi) */             \
      _Pragma("unroll") for (int n_ = 2; n_ < 4; ++n_) {                         \
        LDB8(bf[n_][0], n_, 0); LDB8(bf[n_][1], n_, 1);                          \
      }                                                                          \
      if (T < 15)                                                                \
        STAGE_HALF((Ab_) + 128 * 1024 + (size_t)(T + 1) * 64, &Al[obuf_][1][0]); \
      S_BARRIER; WAIT_LGKM0; SCHED_FENCE;                                        \
      __builtin_amdgcn_s_setprio(1);                                             \
      MF_BLOCK(0, 2)                                                             \
      __builtin_amdgcn_s_setprio(0);                                             \
      S_BARRIER;                                                                 \
      /* ---- phase 3: read A mf4-7; stage B0(T+2); MFMA Q(hi,lo) */             \
      _Pragma("unroll") for (int m_ = 0; m_ < 4; ++m_) {                         \
        LDA8(af[m_][0], 4 + m_, 0); LDA8(af[m_][1], 4 + m_, 1);                  \
      }                                                                          \
      if (T < 14) STAGE_HALF((Bb_) + (size_t)(T + 2) * 64, &Bl[buf_][0][0]);     \
      S_BARRIER; WAIT_LGKM0; SCHED_FENCE;                                        \
      __builtin_amdgcn_s_setprio(1);                                             \
      MF_BLOCK(4, 0)                                                             \
      __builtin_amdgcn_s_setprio(0);                                             \
      S_BARRIER;                                                                 \
      /* ---- phase 4: stage B1(T+2); counted vmcnt; MFMA Q(hi,hi) */            \
      if (T < 14)                                                                \
        STAGE_HALF((Bb_) + 128 * 1024 + (size_t)(T + 2) * 64, &Bl[buf_][1][0]);  \
      if (T < 14) {                                                              \
        asm volatile("s_waitcnt vmcnt(4)" ::: "memory");                         \
      } else {                                                                   \
        asm volatile("s_waitcnt vmcnt(0)" ::: "memory");                         \
      }                                                                          \
      S_BARRIER; SCHED_FENCE;                                                    \
      __builtin_amdgcn_s_setprio(1);                                             \
      MF_BLOCK(4, 2)                                                             \
      __builtin_amdgcn_s_setprio(0);                                             \
      S_BARRIER;                                                                 \
    }                                                                            \
  }

// Fused QKV: blockIdx.y in [0,12): sel = y>>2 picks weight/bias/output; byl = y&3 N-tile.
__global__ __launch_bounds__(512, 2) void gemm_qkv(const unsigned short* __restrict__ A,
                                                   const unsigned short* __restrict__ Wq,
                                                   const unsigned short* __restrict__ Wk,
                                                   const unsigned short* __restrict__ Wv,
                                                   const float* __restrict__ bq,
                                                   const float* __restrict__ bk,
                                                   const float* __restrict__ bv,
                                                   unsigned short* __restrict__ Qo,
                                                   unsigned short* __restrict__ Ko,
                                                   unsigned short* __restrict__ Vt) {
  __shared__ unsigned short Al[2][2][8192];
  __shared__ unsigned short Bl[2][2][8192];
  const int tid = threadIdx.x;
  const int lane = tid & 63, wave = tid >> 6;
  const int l15 = lane & 15, quad = lane >> 4;
  const int wm = wave >> 2, wn = wave & 3;  // 2M x 4N wave grid
  const int bro = (wn & 1) * 64;
  const int bx = blockIdx.x;
  const int sel = blockIdx.y >> 2, byl = blockIdx.y & 3;

  const unsigned short* W = (sel == 0) ? Wq : (sel == 1) ? Wk : Wv;
  const float* bias = (sel == 0) ? bq : (sel == 1) ? bk : bv;
  const unsigned short* Ab = A + (size_t)bx * 256 * 1024;
  const unsigned short* Bb = W + (size_t)byl * 256 * 1024;

  GEMM256_CORE(Ab, Bb)

#pragma unroll
  for (int nf = 0; nf < 4; ++nf) {
    const int cn = byl * 256 + wn * 64 + nf * 16 + l15;
    const float bj = bias[cn];
#pragma unroll
    for (int mf = 0; mf < 8; ++mf) {
      const int r0 = bx * 256 + wm * 128 + mf * 16 + quad * 4;
#pragma unroll
      for (int r = 0; r < 4; ++r) {
        const int row = r0 + r;
        const float v = acc[mf][nf][r] + bj;
        if (sel == 0) {
          Qo[(size_t)row * 1024 + cn] = f2bf_bits(v);
        } else if (sel == 1) {
          Ko[(size_t)row * 1024 + cn] = f2bf_bits(v);
        } else {
          Vt[((size_t)(row >> 13) * 1024 + cn) * 8192 + (row & 8191)] = f2bf_bits(v);
        }
      }
    }
  }
}

// Output GEMM: fp32 out = A * Wo^T + bo
__global__ __launch_bounds__(512, 2) void gemm_out(const unsigned short* __restrict__ A,
                                                   const unsigned short* __restrict__ B,
                                                   const float* __restrict__ bias,
                                                   float* __restrict__ Cf) {
  __shared__ unsigned short Al[2][2][8192];
  __shared__ unsigned short Bl[2][2][8192];
  const int tid = threadIdx.x;
  const int lane = tid & 63, wave = tid >> 6;
  const int l15 = lane & 15, quad = lane >> 4;
  const int wm = wave >> 2, wn = wave & 3;
  const int bro = (wn & 1) * 64;
  const int bx = blockIdx.x;

  const unsigned short* Ab = A + (size_t)bx * 256 * 1024;
  const unsigned short* Bb = B + (size_t)blockIdx.y * 256 * 1024;

  GEMM256_CORE(Ab, Bb)

#pragma unroll
  for (int nf = 0; nf < 4; ++nf) {
    const int cn = blockIdx.y * 256 + wn * 64 + nf * 16 + l15;
    const float bj = bias[cn];
#pragma unroll
    for (int mf = 0; mf < 8; ++mf) {
      const int r0 = bx * 256 + wm * 128 + mf * 16 + quad * 4;
#pragma unroll
      for (int r = 0; r < 4; ++r) Cf[(size_t)(r0 + r) * 1024 + cn] = acc[mf][nf][r] + bj;
    }
  }
}

// ---------------- attention (unchanged) ----------------
__global__ __launch_bounds__(256, 3) void attn_kernel(const unsigned short* __restrict__ Q,
                                                      const unsigned short* __restrict__ Km,
                                                      const unsigned short* __restrict__ Vt,
                                                      unsigned short* __restrict__ O) {
  const int n = blockIdx.x;   // 0..63
  const int bh = blockIdx.y;  // 0..31
  const int b = bh >> 4, h = bh & 15;
  const int tid = threadIdx.x, lane = tid & 63, wave = tid >> 6;
  const int l15 = lane & 15, quad = lane >> 4;

  __shared__ unsigned short Kl[384 * 64];   // 48 KB, chunk-swizzled
  __shared__ unsigned short Ps[4][16 * 40]; // per-wave P strip, pitch 40

  const int base_row = n * 128 - 128;  // seq-local first ctx position

  for (int i = 0; i < 12; ++i) {
    const int c = i * 256 + tid;
    const int row = c >> 3;
    const int qc = (c & 7) ^ (row & 7);
    int gr = base_row + row;
    gr = min(max(gr, 0), 8191);  // clamp; invalid rows masked at use
    gl_lds16(Km + (size_t)(b * 8192 + gr) * 1024 + h * 64 + qc * 8, &Kl[c * 8]);
  }
  __syncthreads();

  const unsigned short* Vbase = Vt + (size_t)bh * 64 * 8192;
  unsigned short* strip = &Ps[wave][0];

  for (int mt = 0; mt < 2; ++mt) {
    const int qt = wave * 2 + mt;
    const int q0 = n * 128 + qt * 16;
    const int qp = q0 + l15;  // S^T: q = l15

    const unsigned short* qptr = Q + (size_t)(b * 8192 + qp) * 1024 + h * 64 + quad * 8;
    const s16x8 bq0 = *(const s16x8*)qptr;
    const s16x8 bq1 = *(const s16x8*)(qptr + 32);

    f32x4 o[4];
#pragma unroll
    for (int dt = 0; dt < 4; ++dt) o[dt] = (f32x4){0.f, 0.f, 0.f, 0.f};
    float lsum = 0.f;

    const int krel0 = qt * 16;

#pragma unroll 1
    for (int p = 0; p < 9; ++p) {
      f32x4 st[2];
#pragma unroll
      for (int tt = 0; tt < 2; ++tt) {
        int rel = krel0 + p * 32 + tt * 16 + l15;
        int rr = min(rel, 383);
        const int ro = rr * 8;
        const int sw = rr & 7;
        const s16x8 ka0 = *(const s16x8*)&Kl[(ro + (quad ^ sw)) * 8];
        const s16x8 ka1 = *(const s16x8*)&Kl[(ro + ((4 + quad) ^ sw)) * 8];
        f32x4 a = (f32x4){0.f, 0.f, 0.f, 0.f};
        a = MFMA16(ka0, bq0, a);
        a = MFMA16(ka1, bq1, a);
        st[tt] = a;
      }
      ushort4 w0, w1;
#pragma unroll
      for (int tt = 0; tt < 2; ++tt) {
        unsigned short* wp = tt ? (unsigned short*)&w1 : (unsigned short*)&w0;
#pragma unroll
        for (int r = 0; r < 4; ++r) {
          const int kp = base_row + krel0 + p * 32 + tt * 16 + quad * 4 + r;
          const int dd = kp - qp;
          const bool ok = (kp >= 0) && (kp < 8192) && (dd >= -128) && (dd <= 128);
          const float pv = ok ? __expf(st[tt][r] * 0.125f) : 0.f;
          lsum += pv;
          wp[r] = f2bf_bits(pv);
        }
      }
      *(ushort4*)&strip[l15 * 40 + quad * 4] = w0;
      *(ushort4*)&strip[l15 * 40 + 16 + quad * 4] = w1;
      const s16x8 pf = *(const s16x8*)&strip[l15 * 40 + quad * 8];
      int kc = base_row + krel0 + p * 32 + quad * 8;
      kc = min(max(kc, 0), 8184);  // clamped lanes multiply P==0
#pragma unroll
      for (int dt = 0; dt < 4; ++dt) {
        const s16x8 va = *(const s16x8*)(Vbase + (size_t)(dt * 16 + l15) * 8192 + kc);
        o[dt] = MFMA16(va, pf, o[dt]);
      }
    }

    lsum += __shfl_xor(lsum, 16, 64);
    lsum += __shfl_xor(lsum, 32, 64);
    const float rinv = 1.f / lsum;
    unsigned short* obase = O + (size_t)(b * 8192 + qp) * 1024 + h * 64;
#pragma unroll
    for (int dt = 0; dt < 4; ++dt) {
      ushort4 w;
      unsigned short* wp = (unsigned short*)&w;
#pragma unroll
      for (int r = 0; r < 4; ++r) wp[r] = f2bf_bits(o[dt][r] * rinv);
      *(ushort4*)(obase + dt * 16 + quad * 4) = w;
    }
  }
}

extern "C" void kernel_launch(void* const* d_in, const int* in_sizes, int n_in, void* d_out,
                              int out_size, void* d_ws, size_t ws_size, hipStream_t stream) {
  const float* x = (const float*)d_in[0];
  const float* Wq = (const float*)d_in[1];
  const float* bq = (const float*)d_in[2];
  const float* Wk = (const float*)d_in[3];
  const float* bk = (const float*)d_in[4];
  const float* Wv = (const float*)d_in[5];
  const float* bv = (const float*)d_in[6];
  const float* Wo = (const float*)d_in[7];
  const float* bo = (const float*)d_in[8];
  float* out = (float*)d_out;

  const int M = 16384, D = 1024;

  unsigned short* xb = (unsigned short*)d_ws;  // [16384,1024] bf16
  unsigned short* qb = xb + (size_t)M * D;     // [16384,1024]
  unsigned short* kb = qb + (size_t)M * D;     // [16384,1024]
  unsigned short* vt = kb + (size_t)M * D;     // [2048,8192] (V transposed)
  unsigned short* ab = vt + (size_t)M * D;     // [16384,1024] attention out
  unsigned short* wqb = ab + (size_t)M * D;    // weights bf16
  unsigned short* wkb = wqb + (size_t)D * D;
  unsigned short* wvb = wkb + (size_t)D * D;
  unsigned short* wob = wvb + (size_t)D * D;

  f2bf_kernel<<<16384, 256, 0, stream>>>(x, xb, M * D / 4);
  f2bf_w4<<<dim3(1024, 4), 256, 0, stream>>>(Wq, Wk, Wv, Wo, wqb, wkb, wvb, wob);

  gemm_qkv<<<dim3(M / 256, 12), 512, 0, stream>>>(xb, wqb, wkb, wvb, bq, bk, bv, qb, kb, vt);

  attn_kernel<<<dim3(64, 32), 256, 0, stream>>>(qb, kb, vt, ab);

  gemm_out<<<dim3(M / 256, D / 256), 512, 0, stream>>>(ab, wob, bo, out);
}

// Round 2
// 407.959 us; speedup vs baseline: 1.0895x; 1.0265x over previous
//
#include <hip/hip_runtime.h>

typedef __attribute__((ext_vector_type(4))) float f32x4;
typedef __attribute__((ext_vector_type(8))) short s16x8;

#define MFMA16(a, b, c) __builtin_amdgcn_mfma_f32_16x16x32_bf16((a), (b), (c), 0, 0, 0)

// round-to-nearest-even fp32 -> bf16 bits
__device__ __forceinline__ unsigned short f2bf_bits(float f) {
  unsigned int u = __float_as_uint(f);
  unsigned int r = (u + 0x7fffu + ((u >> 16) & 1u)) >> 16;
  return (unsigned short)r;
}

__device__ __forceinline__ void gl_lds16(const void* g, void* l) {
  __builtin_amdgcn_global_load_lds((const __attribute__((address_space(1))) void*)g,
                                   (__attribute__((address_space(3))) void*)l, 16, 0, 0);
}

// generic->LDS byte offset (LDS aperture is high-bits only; low 32 = offset)
__device__ __forceinline__ unsigned lds_off(const void* p) {
  return (unsigned)(unsigned long long)p;
}

// inline-asm ds_read_b128: invisible to the compiler's LDS-DMA alias tracking,
// so it cannot insert conservative vmcnt drains before fragment reads.
template <int IMM>
__device__ __forceinline__ s16x8 dsr(unsigned base) {
  s16x8 r;
  asm volatile("ds_read_b128 %0, %1 offset:%2" : "=v"(r) : "v"(base), "n"(IMM));
  return r;
}

// fp32 -> bf16 bulk convert, 4 elems/thread
__global__ __launch_bounds__(256) void f2bf_kernel(const float* __restrict__ in,
                                                   unsigned short* __restrict__ out, int n4) {
  int idx = blockIdx.x * 256 + threadIdx.x;
  int stride = gridDim.x * 256;
  for (int i = idx; i < n4; i += stride) {
    float4 v = ((const float4*)in)[i];
    ushort4 o;
    o.x = f2bf_bits(v.x); o.y = f2bf_bits(v.y);
    o.z = f2bf_bits(v.z); o.w = f2bf_bits(v.w);
    ((ushort4*)out)[i] = o;
  }
}

// convert the 4 [1024,1024] weights in one launch; blockIdx.y selects tensor
__global__ __launch_bounds__(256) void f2bf_w4(const float* __restrict__ w0,
                                               const float* __restrict__ w1,
                                               const float* __restrict__ w2,
                                               const float* __restrict__ w3,
                                               unsigned short* __restrict__ o0,
                                               unsigned short* __restrict__ o1,
                                               unsigned short* __restrict__ o2,
                                               unsigned short* __restrict__ o3) {
  const int s = blockIdx.y;
  const float* in = (s == 0) ? w0 : (s == 1) ? w1 : (s == 2) ? w2 : w3;
  unsigned short* out = (s == 0) ? o0 : (s == 1) ? o1 : (s == 2) ? o2 : o3;
  int i = blockIdx.x * 256 + threadIdx.x;
  float4 v = ((const float4*)in)[i];
  ushort4 o;
  o.x = f2bf_bits(v.x); o.y = f2bf_bits(v.y);
  o.z = f2bf_bits(v.z); o.w = f2bf_bits(v.w);
  ((ushort4*)out)[i] = o;
}

// ============ 256x256-tile, BK=64, 8-wave GEMM core, asm ds_read + counted vmcnt ============
// LDS: Al[2 dbuf][2 half(128rows x 64cols)] + Bl same = 128 KiB. Chunk swizzle: chunk c of
// row r at position c ^ (r&7); applied on global SOURCE addr (stage is linear dest) and on
// the ds_read addr (both-sides rule). Schedule per tile T (1 barrier/phase):
//  P1: rd B23(T) | stage A0(T+1) | MFMA Q(0..3,0..1)
//  P2: rd A47(T) | stage A1(T+1) | MFMA Q(0..3,2..3)
//  P3:           | stage B0(T+2) | MFMA Q(4..7,0..1) | vmcnt(2)  <-- wait BEFORE barrier
//  P4: rd A03,B01(T+1) | stage B1(T+2) | MFMA Q(4..7,2..3)
// vmcnt(2) leaves only B0(T+2) in flight; preceding barrier->all threads' stages of tile
// T+1 complete before any thread's P4 reads of tile T+1 (per-thread counter + barrier).

#define S_BAR __builtin_amdgcn_s_barrier()
#define WAIT_LGKM0 asm volatile("s_waitcnt lgkmcnt(0)")
#define SCHED_FENCE __builtin_amdgcn_sched_barrier(0)
#define PRIO1 __builtin_amdgcn_s_setprio(1)
#define PRIO0 __builtin_amdgcn_s_setprio(0)

// stage one 128x64 half-tile: 2 x global_load_lds(16B) per thread, 512 threads
#define STAGE2(gsrc, ldsdst)                                    \
  gl_lds16((gsrc), (ldsdst) + (size_t)tid * 8);                 \
  gl_lds16((gsrc) + 65536, (ldsdst) + (size_t)tid * 8 + 4096);

#define RD_A03(ax0, ax1)                                        \
  afA[0][0] = dsr<0>(ax0);      afA[0][1] = dsr<0>(ax1);        \
  afA[1][0] = dsr<2048>(ax0);   afA[1][1] = dsr<2048>(ax1);     \
  afA[2][0] = dsr<4096>(ax0);   afA[2][1] = dsr<4096>(ax1);     \
  afA[3][0] = dsr<6144>(ax0);   afA[3][1] = dsr<6144>(ax1);
#define RD_A47(ax0, ax1)                                        \
  afB[0][0] = dsr<8192>(ax0);   afB[0][1] = dsr<8192>(ax1);     \
  afB[1][0] = dsr<10240>(ax0);  afB[1][1] = dsr<10240>(ax1);    \
  afB[2][0] = dsr<12288>(ax0);  afB[2][1] = dsr<12288>(ax1);    \
  afB[3][0] = dsr<14336>(ax0);  afB[3][1] = dsr<14336>(ax1);
#define RD_B01(bx0, bx1)                                        \
  bf[0][0] = dsr<0>(bx0);       bf[0][1] = dsr<0>(bx1);         \
  bf[1][0] = dsr<2048>(bx0);    bf[1][1] = dsr<2048>(bx1);
#define RD_B23(bx0, bx1)                                        \
  bf[2][0] = dsr<4096>(bx0);    bf[2][1] = dsr<4096>(bx1);      \
  bf[3][0] = dsr<6144>(bx0);    bf[3][1] = dsr<6144>(bx1);

#define MM_BLOCK(AF, MB, NB)                                                          \
  _Pragma("unroll") for (int m_ = 0; m_ < 4; ++m_)                                    \
    _Pragma("unroll") for (int n_ = 0; n_ < 2; ++n_) {                                \
      acc[(MB) + m_][(NB) + n_] =                                                     \
          MFMA16(AF[m_][0], bf[(NB) + n_][0], acc[(MB) + m_][(NB) + n_]);             \
      acc[(MB) + m_][(NB) + n_] =                                                     \
          MFMA16(AF[m_][1], bf[(NB) + n_][1], acc[(MB) + m_][(NB) + n_]);             \
    }

#define TILE_FULL(T_, AC0, AC1, AO0, AO1, BC0, BC1, BO0, BO1, ALO_, BLC_)  \
  S_BAR; WAIT_LGKM0; SCHED_FENCE; PRIO1;                                   \
  RD_B23(BC0, BC1);                                                        \
  STAGE2(gA + ((T_) + 1) * 64, (ALO_));                                    \
  MM_BLOCK(afA, 0, 0);                                                     \
  PRIO0;                                                                   \
  S_BAR; WAIT_LGKM0; SCHED_FENCE; PRIO1;                                   \
  RD_A47(AC0, AC1);                                                        \
  STAGE2(gA + 131072 + ((T_) + 1) * 64, (ALO_) + 8192);                    \
  MM_BLOCK(afA, 0, 2);                                                     \
  PRIO0;                                                                   \
  S_BAR; WAIT_LGKM0; SCHED_FENCE; PRIO1;                                   \
  STAGE2(gB + ((T_) + 2) * 64, (BLC_));                                    \
  MM_BLOCK(afB, 4, 0);                                                     \
  PRIO0; SCHED_FENCE;                                                      \
  asm volatile("s_waitcnt vmcnt(2)");                                      \
  S_BAR; SCHED_FENCE; PRIO1;                                               \
  RD_A03(AO0, AO1);                                                        \
  RD_B01(BO0, BO1);                                                        \
  STAGE2(gB + 131072 + ((T_) + 2) * 64, (BLC_) + 8192);                    \
  MM_BLOCK(afB, 4, 2);                                                     \
  PRIO0;

#define GEMM256_CORE(Ab_, Bb_)                                                        \
  f32x4 acc[8][4];                                                                    \
  _Pragma("unroll") for (int mi = 0; mi < 8; ++mi)                                    \
      _Pragma("unroll") for (int ni = 0; ni < 4; ++ni)                                \
          acc[mi][ni] = (f32x4){0.f, 0.f, 0.f, 0.f};                                  \
  s16x8 afA[4][2], afB[4][2], bf[4][2];                                               \
  {                                                                                   \
    const int r_ = tid >> 3;                                                          \
    const int c_ = (tid & 7) ^ (r_ & 7);                                              \
    const unsigned short* gA = (Ab_) + (size_t)r_ * 1024 + c_ * 8;                    \
    const unsigned short* gB = (Bb_) + (size_t)r_ * 1024 + c_ * 8;                    \
    const unsigned x0 = (unsigned)((quad ^ (l15 & 7)) * 16);                          \
    const unsigned x1 = (unsigned)(((4 + quad) ^ (l15 & 7)) * 16);                    \
    const unsigned aW = (unsigned)(l15 * 128);                                        \
    const unsigned bW = (unsigned)(bro * 128 + l15 * 128);                            \
    const unsigned a0x0 = lds_off(&Al[0][wm][0]) + aW + x0;                           \
    const unsigned a0x1 = lds_off(&Al[0][wm][0]) + aW + x1;                           \
    const unsigned a1x0 = lds_off(&Al[1][wm][0]) + aW + x0;                           \
    const unsigned a1x1 = lds_off(&Al[1][wm][0]) + aW + x1;                           \
    const unsigned b0x0 = lds_off(&Bl[0][wn >> 1][0]) + bW + x0;                      \
    const unsigned b0x1 = lds_off(&Bl[0][wn >> 1][0]) + bW + x1;                      \
    const unsigned b1x0 = lds_off(&Bl[1][wn >> 1][0]) + bW + x0;                      \
    const unsigned b1x1 = lds_off(&Bl[1][wn >> 1][0]) + bW + x1;                      \
    /* prologue: tile0 (A0,A1,B0,B1) -> buf0, tile1 B halves -> buf1 */               \
    STAGE2(gA, (&Al[0][0][0]));                                                       \
    STAGE2(gA + 131072, (&Al[0][0][0]) + 8192);                                       \
    STAGE2(gB, (&Bl[0][0][0]));                                                       \
    STAGE2(gB + 131072, (&Bl[0][0][0]) + 8192);                                       \
    STAGE2(gB + 64, (&Bl[1][0][0]));                                                  \
    STAGE2(gB + 131072 + 64, (&Bl[1][0][0]) + 8192);                                  \
    SCHED_FENCE;                                                                      \
    asm volatile("s_waitcnt vmcnt(4)"); /* tile0 complete; B(1) in flight */          \
    S_BAR; SCHED_FENCE;                                                               \
    RD_A03(a0x0, a0x1);                                                               \
    RD_B01(b0x0, b0x1);                                                               \
    _Pragma("unroll 1") for (int Tp = 0; Tp < 7; ++Tp) {                              \
      const int T0 = Tp * 2;                                                          \
      TILE_FULL(T0, a0x0, a0x1, a1x0, a1x1, b0x0, b0x1, b1x0, b1x1,                   \
                (&Al[1][0][0]), (&Bl[0][0][0]));                                      \
      TILE_FULL(T0 + 1, a1x0, a1x1, a0x0, a0x1, b1x0, b1x1, b0x0, b0x1,               \
                (&Al[0][0][0]), (&Bl[1][0][0]));                                      \
    }                                                                                 \
    /* ---- T = 14 (buf0): stage A(15) only; vmcnt(0) at P3 end ---- */               \
    S_BAR; WAIT_LGKM0; SCHED_FENCE; PRIO1;                                            \
    RD_B23(b0x0, b0x1);                                                               \
    STAGE2(gA + 15 * 64, (&Al[1][0][0]));                                             \
    MM_BLOCK(afA, 0, 0);                                                              \
    PRIO0;                                                                            \
    S_BAR; WAIT_LGKM0; SCHED_FENCE; PRIO1;                                            \
    RD_A47(a0x0, a0x1);                                                               \
    STAGE2(gA + 131072 + 15 * 64, (&Al[1][0][0]) + 8192);                             \
    MM_BLOCK(afA, 0, 2);                                                              \
    PRIO0;                                                                            \
    S_BAR; WAIT_LGKM0; SCHED_FENCE; PRIO1;                                            \
    MM_BLOCK(afB, 4, 0);                                                              \
    PRIO0; SCHED_FENCE;                                                               \
    asm volatile("s_waitcnt vmcnt(0)");                                               \
    S_BAR; SCHED_FENCE; PRIO1;                                                        \
    RD_A03(a1x0, a1x1);                                                               \
    RD_B01(b1x0, b1x1);                                                               \
    MM_BLOCK(afB, 4, 2);                                                              \
    PRIO0;                                                                            \
    /* ---- T = 15 (buf1): no stages, no vmcnt ---- */                                \
    S_BAR; WAIT_LGKM0; SCHED_FENCE; PRIO1;                                            \
    RD_B23(b1x0, b1x1);                                                               \
    MM_BLOCK(afA, 0, 0);                                                              \
    PRIO0;                                                                            \
    S_BAR; WAIT_LGKM0; SCHED_FENCE; PRIO1;                                            \
    RD_A47(a1x0, a1x1);                                                               \
    MM_BLOCK(afA, 0, 2);                                                              \
    PRIO0;                                                                            \
    S_BAR; WAIT_LGKM0; SCHED_FENCE; PRIO1;                                            \
    MM_BLOCK(afB, 4, 0);                                                              \
    PRIO0;                                                                            \
    S_BAR; SCHED_FENCE; PRIO1;                                                        \
    MM_BLOCK(afB, 4, 2);                                                              \
    PRIO0;                                                                            \
  }

// Fused QKV: blockIdx.y in [0,12): sel = y>>2 picks weight/bias/output; byl = y&3 N-tile.
__global__ __launch_bounds__(512, 2) void gemm_qkv(const unsigned short* __restrict__ A,
                                                   const unsigned short* __restrict__ Wq,
                                                   const unsigned short* __restrict__ Wk,
                                                   const unsigned short* __restrict__ Wv,
                                                   const float* __restrict__ bq,
                                                   const float* __restrict__ bk,
                                                   const float* __restrict__ bv,
                                                   unsigned short* __restrict__ Qo,
                                                   unsigned short* __restrict__ Ko,
                                                   unsigned short* __restrict__ Vt) {
  __shared__ unsigned short Al[2][2][8192];
  __shared__ unsigned short Bl[2][2][8192];
  const int tid = threadIdx.x;
  const int lane = tid & 63, wave = tid >> 6;
  const int l15 = lane & 15, quad = lane >> 4;
  const int wm = wave >> 2, wn = wave & 3;  // 2M x 4N wave grid
  const int bro = (wn & 1) * 64;
  const int bx = blockIdx.x;
  const int sel = blockIdx.y >> 2, byl = blockIdx.y & 3;

  const unsigned short* W = (sel == 0) ? Wq : (sel == 1) ? Wk : Wv;
  const float* bias = (sel == 0) ? bq : (sel == 1) ? bk : bv;
  const unsigned short* Ab = A + (size_t)bx * 256 * 1024;
  const unsigned short* Bb = W + (size_t)byl * 256 * 1024;

  GEMM256_CORE(Ab, Bb)

#pragma unroll
  for (int nf = 0; nf < 4; ++nf) {
    const int cn = byl * 256 + wn * 64 + nf * 16 + l15;
    const float bj = bias[cn];
#pragma unroll
    for (int mf = 0; mf < 8; ++mf) {
      const int r0 = bx * 256 + wm * 128 + mf * 16 + quad * 4;
#pragma unroll
      for (int r = 0; r < 4; ++r) {
        const int row = r0 + r;
        const float v = acc[mf][nf][r] + bj;
        if (sel == 0) {
          Qo[(size_t)row * 1024 + cn] = f2bf_bits(v);
        } else if (sel == 1) {
          Ko[(size_t)row * 1024 + cn] = f2bf_bits(v);
        } else {
          Vt[((size_t)(row >> 13) * 1024 + cn) * 8192 + (row & 8191)] = f2bf_bits(v);
        }
      }
    }
  }
}

// Output GEMM: fp32 out = A * Wo^T + bo
__global__ __launch_bounds__(512, 2) void gemm_out(const unsigned short* __restrict__ A,
                                                   const unsigned short* __restrict__ B,
                                                   const float* __restrict__ bias,
                                                   float* __restrict__ Cf) {
  __shared__ unsigned short Al[2][2][8192];
  __shared__ unsigned short Bl[2][2][8192];
  const int tid = threadIdx.x;
  const int lane = tid & 63, wave = tid >> 6;
  const int l15 = lane & 15, quad = lane >> 4;
  const int wm = wave >> 2, wn = wave & 3;
  const int bro = (wn & 1) * 64;
  const int bx = blockIdx.x;

  const unsigned short* Ab = A + (size_t)bx * 256 * 1024;
  const unsigned short* Bb = B + (size_t)blockIdx.y * 256 * 1024;

  GEMM256_CORE(Ab, Bb)

#pragma unroll
  for (int nf = 0; nf < 4; ++nf) {
    const int cn = blockIdx.y * 256 + wn * 64 + nf * 16 + l15;
    const float bj = bias[cn];
#pragma unroll
    for (int mf = 0; mf < 8; ++mf) {
      const int r0 = bx * 256 + wm * 128 + mf * 16 + quad * 4;
#pragma unroll
      for (int r = 0; r < 4; ++r) Cf[(size_t)(r0 + r) * 1024 + cn] = acc[mf][nf][r] + bj;
    }
  }
}

// ---------------- attention (unchanged) ----------------
__global__ __launch_bounds__(256, 3) void attn_kernel(const unsigned short* __restrict__ Q,
                                                      const unsigned short* __restrict__ Km,
                                                      const unsigned short* __restrict__ Vt,
                                                      unsigned short* __restrict__ O) {
  const int n = blockIdx.x;   // 0..63
  const int bh = blockIdx.y;  // 0..31
  const int b = bh >> 4, h = bh & 15;
  const int tid = threadIdx.x, lane = tid & 63, wave = tid >> 6;
  const int l15 = lane & 15, quad = lane >> 4;

  __shared__ unsigned short Kl[384 * 64];   // 48 KB, chunk-swizzled
  __shared__ unsigned short Ps[4][16 * 40]; // per-wave P strip, pitch 40

  const int base_row = n * 128 - 128;  // seq-local first ctx position

  for (int i = 0; i < 12; ++i) {
    const int c = i * 256 + tid;
    const int row = c >> 3;
    const int qc = (c & 7) ^ (row & 7);
    int gr = base_row + row;
    gr = min(max(gr, 0), 8191);  // clamp; invalid rows masked at use
    gl_lds16(Km + (size_t)(b * 8192 + gr) * 1024 + h * 64 + qc * 8, &Kl[c * 8]);
  }
  __syncthreads();

  const unsigned short* Vbase = Vt + (size_t)bh * 64 * 8192;
  unsigned short* strip = &Ps[wave][0];

  for (int mt = 0; mt < 2; ++mt) {
    const int qt = wave * 2 + mt;
    const int q0 = n * 128 + qt * 16;
    const int qp = q0 + l15;  // S^T: q = l15

    const unsigned short* qptr = Q + (size_t)(b * 8192 + qp) * 1024 + h * 64 + quad * 8;
    const s16x8 bq0 = *(const s16x8*)qptr;
    const s16x8 bq1 = *(const s16x8*)(qptr + 32);

    f32x4 o[4];
#pragma unroll
    for (int dt = 0; dt < 4; ++dt) o[dt] = (f32x4){0.f, 0.f, 0.f, 0.f};
    float lsum = 0.f;

    const int krel0 = qt * 16;

#pragma unroll 1
    for (int p = 0; p < 9; ++p) {
      f32x4 st[2];
#pragma unroll
      for (int tt = 0; tt < 2; ++tt) {
        int rel = krel0 + p * 32 + tt * 16 + l15;
        int rr = min(rel, 383);
        const int ro = rr * 8;
        const int sw = rr & 7;
        const s16x8 ka0 = *(const s16x8*)&Kl[(ro + (quad ^ sw)) * 8];
        const s16x8 ka1 = *(const s16x8*)&Kl[(ro + ((4 + quad) ^ sw)) * 8];
        f32x4 a = (f32x4){0.f, 0.f, 0.f, 0.f};
        a = MFMA16(ka0, bq0, a);
        a = MFMA16(ka1, bq1, a);
        st[tt] = a;
      }
      ushort4 w0, w1;
#pragma unroll
      for (int tt = 0; tt < 2; ++tt) {
        unsigned short* wp = tt ? (unsigned short*)&w1 : (unsigned short*)&w0;
#pragma unroll
        for (int r = 0; r < 4; ++r) {
          const int kp = base_row + krel0 + p * 32 + tt * 16 + quad * 4 + r;
          const int dd = kp - qp;
          const bool ok = (kp >= 0) && (kp < 8192) && (dd >= -128) && (dd <= 128);
          const float pv = ok ? __expf(st[tt][r] * 0.125f) : 0.f;
          lsum += pv;
          wp[r] = f2bf_bits(pv);
        }
      }
      *(ushort4*)&strip[l15 * 40 + quad * 4] = w0;
      *(ushort4*)&strip[l15 * 40 + 16 + quad * 4] = w1;
      const s16x8 pf = *(const s16x8*)&strip[l15 * 40 + quad * 8];
      int kc = base_row + krel0 + p * 32 + quad * 8;
      kc = min(max(kc, 0), 8184);  // clamped lanes multiply P==0
#pragma unroll
      for (int dt = 0; dt < 4; ++dt) {
        const s16x8 va = *(const s16x8*)(Vbase + (size_t)(dt * 16 + l15) * 8192 + kc);
        o[dt] = MFMA16(va, pf, o[dt]);
      }
    }

    lsum += __shfl_xor(lsum, 16, 64);
    lsum += __shfl_xor(lsum, 32, 64);
    const float rinv = 1.f / lsum;
    unsigned short* obase = O + (size_t)(b * 8192 + qp) * 1024 + h * 64;
#pragma unroll
    for (int dt = 0; dt < 4; ++dt) {
      ushort4 w;
      unsigned short* wp = (unsigned short*)&w;
#pragma unroll
      for (int r = 0; r < 4; ++r) wp[r] = f2bf_bits(o[dt][r] * rinv);
      *(ushort4*)(obase + dt * 16 + quad * 4) = w;
    }
  }
}

extern "C" void kernel_launch(void* const* d_in, const int* in_sizes, int n_in, void* d_out,
                              int out_size, void* d_ws, size_t ws_size, hipStream_t stream) {
  const float* x = (const float*)d_in[0];
  const float* Wq = (const float*)d_in[1];
  const float* bq = (const float*)d_in[2];
  const float* Wk = (const float*)d_in[3];
  const float* bk = (const float*)d_in[4];
  const float* Wv = (const float*)d_in[5];
  const float* bv = (const float*)d_in[6];
  const float* Wo = (const float*)d_in[7];
  const float* bo = (const float*)d_in[8];
  float* out = (float*)d_out;

  const int M = 16384, D = 1024;

  unsigned short* xb = (unsigned short*)d_ws;  // [16384,1024] bf16
  unsigned short* qb = xb + (size_t)M * D;     // [16384,1024]
  unsigned short* kb = qb + (size_t)M * D;     // [16384,1024]
  unsigned short* vt = kb + (size_t)M * D;     // [2048,8192] (V transposed)
  unsigned short* ab = vt + (size_t)M * D;     // [16384,1024] attention out
  unsigned short* wqb = ab + (size_t)M * D;    // weights bf16
  unsigned short* wkb = wqb + (size_t)D * D;
  unsigned short* wvb = wkb + (size_t)D * D;
  unsigned short* wob = wvb + (size_t)D * D;

  f2bf_kernel<<<16384, 256, 0, stream>>>(x, xb, M * D / 4);
  f2bf_w4<<<dim3(1024, 4), 256, 0, stream>>>(Wq, Wk, Wv, Wo, wqb, wkb, wvb, wob);

  gemm_qkv<<<dim3(M / 256, 12), 512, 0, stream>>>(xb, wqb, wkb, wvb, bq, bk, bv, qb, kb, vt);

  attn_kernel<<<dim3(64, 32), 256, 0, stream>>>(qb, kb, vt, ab);

  gemm_out<<<dim3(M / 256, D / 256), 512, 0, stream>>>(ab, wob, bo, out);
}

// Round 3
// 400.078 us; speedup vs baseline: 1.1109x; 1.0197x over previous
//
#include <hip/hip_runtime.h>

typedef __attribute__((ext_vector_type(4))) float f32x4;
typedef __attribute__((ext_vector_type(8))) short s16x8;

#define MFMA16(a, b, c) __builtin_amdgcn_mfma_f32_16x16x32_bf16((a), (b), (c), 0, 0, 0)

// round-to-nearest-even fp32 -> bf16 bits
__device__ __forceinline__ unsigned short f2bf_bits(float f) {
  unsigned int u = __float_as_uint(f);
  unsigned int r = (u + 0x7fffu + ((u >> 16) & 1u)) >> 16;
  return (unsigned short)r;
}

__device__ __forceinline__ void gl_lds16(const void* g, void* l) {
  __builtin_amdgcn_global_load_lds((const __attribute__((address_space(1))) void*)g,
                                   (__attribute__((address_space(3))) void*)l, 16, 0, 0);
}

// generic->LDS byte offset (LDS aperture is high-bits only; low 32 = offset)
__device__ __forceinline__ unsigned lds_off(const void* p) {
  return (unsigned)(unsigned long long)p;
}

// inline-asm ds_read_b128: invisible to the compiler's LDS-DMA alias tracking,
// so it cannot insert conservative vmcnt drains before fragment reads.
template <int IMM>
__device__ __forceinline__ s16x8 dsr(unsigned base) {
  s16x8 r;
  asm volatile("ds_read_b128 %0, %1 offset:%2" : "=v"(r) : "v"(base), "n"(IMM));
  return r;
}

// fp32 -> bf16 bulk convert, 4 elems/thread
__global__ __launch_bounds__(256) void f2bf_kernel(const float* __restrict__ in,
                                                   unsigned short* __restrict__ out, int n4) {
  int idx = blockIdx.x * 256 + threadIdx.x;
  int stride = gridDim.x * 256;
  for (int i = idx; i < n4; i += stride) {
    float4 v = ((const float4*)in)[i];
    ushort4 o;
    o.x = f2bf_bits(v.x); o.y = f2bf_bits(v.y);
    o.z = f2bf_bits(v.z); o.w = f2bf_bits(v.w);
    ((ushort4*)out)[i] = o;
  }
}

// convert the 4 [1024,1024] weights in one launch; blockIdx.y selects tensor
__global__ __launch_bounds__(256) void f2bf_w4(const float* __restrict__ w0,
                                               const float* __restrict__ w1,
                                               const float* __restrict__ w2,
                                               const float* __restrict__ w3,
                                               unsigned short* __restrict__ o0,
                                               unsigned short* __restrict__ o1,
                                               unsigned short* __restrict__ o2,
                                               unsigned short* __restrict__ o3) {
  const int s = blockIdx.y;
  const float* in = (s == 0) ? w0 : (s == 1) ? w1 : (s == 2) ? w2 : w3;
  unsigned short* out = (s == 0) ? o0 : (s == 1) ? o1 : (s == 2) ? o2 : o3;
  int i = blockIdx.x * 256 + threadIdx.x;
  float4 v = ((const float4*)in)[i];
  ushort4 o;
  o.x = f2bf_bits(v.x); o.y = f2bf_bits(v.y);
  o.z = f2bf_bits(v.z); o.w = f2bf_bits(v.w);
  ((ushort4*)out)[i] = o;
}

// ======== 256x256-tile, BK=64, 8-wave GEMM, m201-style two-barrier phases ========
// Per tile T, 4 phases; each phase = {ds_reads for THIS phase's MFMA; 1 half-tile
// stage; s_barrier; lgkmcnt(0); PURE 16-MFMA cluster; s_barrier}. MFMA clusters
// contain no LDS/VMEM issues (LDS-queue-fill stalls land at the barrier, not inside
// the MFMA burst). A staged 1 tile ahead, B 2 tiles ahead. One counted vmcnt(2) per
// tile at P3, BEFORE its trailing barrier (wait -> barrier -> read). Never 0 until T=14.
// In-flight at P3(T) wait: B0/B1(T+1), A0/A1(T+1), B0(T+2) = 10 loads; vmcnt(2)
// forces all of tile T+1 landed, leaves B0(T+2) in flight.

#define S_BAR __builtin_amdgcn_s_barrier()
#define WAIT_LGKM0 asm volatile("s_waitcnt lgkmcnt(0)")
#define SCHED_FENCE __builtin_amdgcn_sched_barrier(0)
#define PRIO1 __builtin_amdgcn_s_setprio(1)
#define PRIO0 __builtin_amdgcn_s_setprio(0)
#define VM_W2 asm volatile("s_waitcnt vmcnt(2)")
#define VM_W0 asm volatile("s_waitcnt vmcnt(0)")
#define VM_NONE

// stage one 128x64 half-tile: 2 x global_load_lds(16B) per thread, 512 threads
#define STAGE2(gsrc, ldsdst)                                    \
  gl_lds16((gsrc), (ldsdst) + (size_t)tid * 8);                 \
  gl_lds16((gsrc) + 65536, (ldsdst) + (size_t)tid * 8 + 4096);

#define RD_A03(ax0, ax1)                                        \
  afA[0][0] = dsr<0>(ax0);      afA[0][1] = dsr<0>(ax1);        \
  afA[1][0] = dsr<2048>(ax0);   afA[1][1] = dsr<2048>(ax1);     \
  afA[2][0] = dsr<4096>(ax0);   afA[2][1] = dsr<4096>(ax1);     \
  afA[3][0] = dsr<6144>(ax0);   afA[3][1] = dsr<6144>(ax1);
#define RD_A47(ax0, ax1)                                        \
  afB[0][0] = dsr<8192>(ax0);   afB[0][1] = dsr<8192>(ax1);     \
  afB[1][0] = dsr<10240>(ax0);  afB[1][1] = dsr<10240>(ax1);    \
  afB[2][0] = dsr<12288>(ax0);  afB[2][1] = dsr<12288>(ax1);    \
  afB[3][0] = dsr<14336>(ax0);  afB[3][1] = dsr<14336>(ax1);
#define RD_B01(bx0, bx1)                                        \
  bf[0][0] = dsr<0>(bx0);       bf[0][1] = dsr<0>(bx1);         \
  bf[1][0] = dsr<2048>(bx0);    bf[1][1] = dsr<2048>(bx1);
#define RD_B23(bx0, bx1)                                        \
  bf[2][0] = dsr<4096>(bx0);    bf[2][1] = dsr<4096>(bx1);      \
  bf[3][0] = dsr<6144>(bx0);    bf[3][1] = dsr<6144>(bx1);

#define MM_BLOCK(AF, MB, NB)                                                          \
  _Pragma("unroll") for (int m_ = 0; m_ < 4; ++m_)                                    \
    _Pragma("unroll") for (int n_ = 0; n_ < 2; ++n_) {                                \
      acc[(MB) + m_][(NB) + n_] =                                                     \
          MFMA16(AF[m_][0], bf[(NB) + n_][0], acc[(MB) + m_][(NB) + n_]);             \
      acc[(MB) + m_][(NB) + n_] =                                                     \
          MFMA16(AF[m_][1], bf[(NB) + n_][1], acc[(MB) + m_][(NB) + n_]);             \
    }

// One tile, m201-style. STA_/STB_ compile-time 0/1; VMW_ is a statement macro.
#define TILE_M201(T_, AC0, AC1, BC0, BC1, ALO_, BLC_, STA_, STB_, VMW_)        \
  /* P1: rd A03(T), B01(T); stage A0(T+1) */                                    \
  RD_A03(AC0, AC1);                                                             \
  RD_B01(BC0, BC1);                                                             \
  if (STA_) { STAGE2(gA + ((T_) + 1) * 64, (ALO_)); }                           \
  S_BAR; WAIT_LGKM0; SCHED_FENCE;                                               \
  PRIO1; MM_BLOCK(afA, 0, 0); PRIO0;                                            \
  S_BAR;                                                                        \
  /* P2: rd B23(T); stage A1(T+1) */                                            \
  RD_B23(BC0, BC1);                                                             \
  if (STA_) { STAGE2(gA + 131072 + ((T_) + 1) * 64, (ALO_) + 8192); }           \
  S_BAR; WAIT_LGKM0; SCHED_FENCE;                                               \
  PRIO1; MM_BLOCK(afA, 0, 2); PRIO0;                                            \
  S_BAR;                                                                        \
  /* P3: rd A47(T); stage B0(T+2); counted vmcnt BEFORE trailing barrier */     \
  RD_A47(AC0, AC1);                                                             \
  if (STB_) { STAGE2(gB + ((T_) + 2) * 64, (BLC_)); }                           \
  S_BAR; WAIT_LGKM0; SCHED_FENCE;                                               \
  PRIO1; MM_BLOCK(afB, 4, 0); PRIO0;                                            \
  VMW_;                                                                         \
  S_BAR;                                                                        \
  /* P4: stage B1(T+2); pure MFMA Q(4,2); no trailing barrier (proven safe) */  \
  if (STB_) { STAGE2(gB + 131072 + ((T_) + 2) * 64, (BLC_) + 8192); }           \
  SCHED_FENCE;                                                                  \
  PRIO1; MM_BLOCK(afB, 4, 2); PRIO0;

#define GEMM256_CORE(Ab_, Bb_)                                                        \
  f32x4 acc[8][4];                                                                    \
  _Pragma("unroll") for (int mi = 0; mi < 8; ++mi)                                    \
      _Pragma("unroll") for (int ni = 0; ni < 4; ++ni)                                \
          acc[mi][ni] = (f32x4){0.f, 0.f, 0.f, 0.f};                                  \
  s16x8 afA[4][2], afB[4][2], bf[4][2];                                               \
  {                                                                                   \
    const int r_ = tid >> 3;                                                          \
    const int c_ = (tid & 7) ^ (r_ & 7);                                              \
    const unsigned short* gA = (Ab_) + (size_t)r_ * 1024 + c_ * 8;                    \
    const unsigned short* gB = (Bb_) + (size_t)r_ * 1024 + c_ * 8;                    \
    const unsigned x0 = (unsigned)((quad ^ (l15 & 7)) * 16);                          \
    const unsigned x1 = (unsigned)(((4 + quad) ^ (l15 & 7)) * 16);                    \
    const unsigned aW = (unsigned)(l15 * 128);                                        \
    const unsigned bW = (unsigned)(bro * 128 + l15 * 128);                            \
    const unsigned a0x0 = lds_off(&Al[0][wm][0]) + aW + x0;                           \
    const unsigned a0x1 = lds_off(&Al[0][wm][0]) + aW + x1;                           \
    const unsigned a1x0 = lds_off(&Al[1][wm][0]) + aW + x0;                           \
    const unsigned a1x1 = lds_off(&Al[1][wm][0]) + aW + x1;                           \
    const unsigned b0x0 = lds_off(&Bl[0][wn >> 1][0]) + bW + x0;                      \
    const unsigned b0x1 = lds_off(&Bl[0][wn >> 1][0]) + bW + x1;                      \
    const unsigned b1x0 = lds_off(&Bl[1][wn >> 1][0]) + bW + x0;                      \
    const unsigned b1x1 = lds_off(&Bl[1][wn >> 1][0]) + bW + x1;                      \
    /* prologue: tile0 (A0,A1,B0,B1) -> buf0; tile1 B halves -> buf1 */               \
    STAGE2(gA, (&Al[0][0][0]));                                                       \
    STAGE2(gA + 131072, (&Al[0][0][0]) + 8192);                                       \
    STAGE2(gB, (&Bl[0][0][0]));                                                       \
    STAGE2(gB + 131072, (&Bl[0][0][0]) + 8192);                                       \
    STAGE2(gB + 64, (&Bl[1][0][0]));                                                  \
    STAGE2(gB + 131072 + 64, (&Bl[1][0][0]) + 8192);                                  \
    SCHED_FENCE;                                                                      \
    asm volatile("s_waitcnt vmcnt(4)"); /* tile0 landed; B(1) in flight */            \
    S_BAR; SCHED_FENCE;                                                               \
    _Pragma("unroll 1") for (int Tp = 0; Tp < 7; ++Tp) {                              \
      const int T0 = Tp * 2;                                                          \
      TILE_M201(T0, a0x0, a0x1, b0x0, b0x1, (&Al[1][0][0]), (&Bl[0][0][0]),           \
                1, 1, VM_W2);                                                         \
      TILE_M201(T0 + 1, a1x0, a1x1, b1x0, b1x1, (&Al[0][0][0]), (&Bl[1][0][0]),       \
                1, 1, VM_W2);                                                         \
    }                                                                                 \
    /* T = 14 (buf0): stage A(15) only; vmcnt(0) at P3 */                             \
    TILE_M201(14, a0x0, a0x1, b0x0, b0x1, (&Al[1][0][0]), (&Bl[0][0][0]),             \
              1, 0, VM_W0);                                                           \
    /* T = 15 (buf1): no stages, no vmcnt */                                          \
    TILE_M201(15, a1x0, a1x1, b1x0, b1x1, (&Al[0][0][0]), (&Bl[1][0][0]),             \
              0, 0, VM_NONE);                                                         \
  }

// Fused QKV: blockIdx.y in [0,12): sel = y>>2 picks weight/bias/output; byl = y&3 N-tile.
__global__ __launch_bounds__(512, 2) void gemm_qkv(const unsigned short* __restrict__ A,
                                                   const unsigned short* __restrict__ Wq,
                                                   const unsigned short* __restrict__ Wk,
                                                   const unsigned short* __restrict__ Wv,
                                                   const float* __restrict__ bq,
                                                   const float* __restrict__ bk,
                                                   const float* __restrict__ bv,
                                                   unsigned short* __restrict__ Qo,
                                                   unsigned short* __restrict__ Ko,
                                                   unsigned short* __restrict__ Vt) {
  __shared__ unsigned short Al[2][2][8192];
  __shared__ unsigned short Bl[2][2][8192];
  const int tid = threadIdx.x;
  const int lane = tid & 63, wave = tid >> 6;
  const int l15 = lane & 15, quad = lane >> 4;
  const int wm = wave >> 2, wn = wave & 3;  // 2M x 4N wave grid
  const int bro = (wn & 1) * 64;
  const int bx = blockIdx.x;
  const int sel = blockIdx.y >> 2, byl = blockIdx.y & 3;

  const unsigned short* W = (sel == 0) ? Wq : (sel == 1) ? Wk : Wv;
  const float* bias = (sel == 0) ? bq : (sel == 1) ? bk : bv;
  const unsigned short* Ab = A + (size_t)bx * 256 * 1024;
  const unsigned short* Bb = W + (size_t)byl * 256 * 1024;

  GEMM256_CORE(Ab, Bb)

#pragma unroll
  for (int nf = 0; nf < 4; ++nf) {
    const int cn = byl * 256 + wn * 64 + nf * 16 + l15;
    const float bj = bias[cn];
#pragma unroll
    for (int mf = 0; mf < 8; ++mf) {
      const int r0 = bx * 256 + wm * 128 + mf * 16 + quad * 4;
#pragma unroll
      for (int r = 0; r < 4; ++r) {
        const int row = r0 + r;
        const float v = acc[mf][nf][r] + bj;
        if (sel == 0) {
          Qo[(size_t)row * 1024 + cn] = f2bf_bits(v);
        } else if (sel == 1) {
          Ko[(size_t)row * 1024 + cn] = f2bf_bits(v);
        } else {
          Vt[((size_t)(row >> 13) * 1024 + cn) * 8192 + (row & 8191)] = f2bf_bits(v);
        }
      }
    }
  }
}

// Output GEMM: fp32 out = A * Wo^T + bo
__global__ __launch_bounds__(512, 2) void gemm_out(const unsigned short* __restrict__ A,
                                                   const unsigned short* __restrict__ B,
                                                   const float* __restrict__ bias,
                                                   float* __restrict__ Cf) {
  __shared__ unsigned short Al[2][2][8192];
  __shared__ unsigned short Bl[2][2][8192];
  const int tid = threadIdx.x;
  const int lane = tid & 63, wave = tid >> 6;
  const int l15 = lane & 15, quad = lane >> 4;
  const int wm = wave >> 2, wn = wave & 3;
  const int bro = (wn & 1) * 64;
  const int bx = blockIdx.x;

  const unsigned short* Ab = A + (size_t)bx * 256 * 1024;
  const unsigned short* Bb = B + (size_t)blockIdx.y * 256 * 1024;

  GEMM256_CORE(Ab, Bb)

#pragma unroll
  for (int nf = 0; nf < 4; ++nf) {
    const int cn = blockIdx.y * 256 + wn * 64 + nf * 16 + l15;
    const float bj = bias[cn];
#pragma unroll
    for (int mf = 0; mf < 8; ++mf) {
      const int r0 = bx * 256 + wm * 128 + mf * 16 + quad * 4;
#pragma unroll
      for (int r = 0; r < 4; ++r) Cf[(size_t)(r0 + r) * 1024 + cn] = acc[mf][nf][r] + bj;
    }
  }
}

// ---------------- attention (unchanged) ----------------
__global__ __launch_bounds__(256, 3) void attn_kernel(const unsigned short* __restrict__ Q,
                                                      const unsigned short* __restrict__ Km,
                                                      const unsigned short* __restrict__ Vt,
                                                      unsigned short* __restrict__ O) {
  const int n = blockIdx.x;   // 0..63
  const int bh = blockIdx.y;  // 0..31
  const int b = bh >> 4, h = bh & 15;
  const int tid = threadIdx.x, lane = tid & 63, wave = tid >> 6;
  const int l15 = lane & 15, quad = lane >> 4;

  __shared__ unsigned short Kl[384 * 64];   // 48 KB, chunk-swizzled
  __shared__ unsigned short Ps[4][16 * 40]; // per-wave P strip, pitch 40

  const int base_row = n * 128 - 128;  // seq-local first ctx position

  for (int i = 0; i < 12; ++i) {
    const int c = i * 256 + tid;
    const int row = c >> 3;
    const int qc = (c & 7) ^ (row & 7);
    int gr = base_row + row;
    gr = min(max(gr, 0), 8191);  // clamp; invalid rows masked at use
    gl_lds16(Km + (size_t)(b * 8192 + gr) * 1024 + h * 64 + qc * 8, &Kl[c * 8]);
  }
  __syncthreads();

  const unsigned short* Vbase = Vt + (size_t)bh * 64 * 8192;
  unsigned short* strip = &Ps[wave][0];

  for (int mt = 0; mt < 2; ++mt) {
    const int qt = wave * 2 + mt;
    const int q0 = n * 128 + qt * 16;
    const int qp = q0 + l15;  // S^T: q = l15

    const unsigned short* qptr = Q + (size_t)(b * 8192 + qp) * 1024 + h * 64 + quad * 8;
    const s16x8 bq0 = *(const s16x8*)qptr;
    const s16x8 bq1 = *(const s16x8*)(qptr + 32);

    f32x4 o[4];
#pragma unroll
    for (int dt = 0; dt < 4; ++dt) o[dt] = (f32x4){0.f, 0.f, 0.f, 0.f};
    float lsum = 0.f;

    const int krel0 = qt * 16;

#pragma unroll 1
    for (int p = 0; p < 9; ++p) {
      f32x4 st[2];
#pragma unroll
      for (int tt = 0; tt < 2; ++tt) {
        int rel = krel0 + p * 32 + tt * 16 + l15;
        int rr = min(rel, 383);
        const int ro = rr * 8;
        const int sw = rr & 7;
        const s16x8 ka0 = *(const s16x8*)&Kl[(ro + (quad ^ sw)) * 8];
        const s16x8 ka1 = *(const s16x8*)&Kl[(ro + ((4 + quad) ^ sw)) * 8];
        f32x4 a = (f32x4){0.f, 0.f, 0.f, 0.f};
        a = MFMA16(ka0, bq0, a);
        a = MFMA16(ka1, bq1, a);
        st[tt] = a;
      }
      ushort4 w0, w1;
#pragma unroll
      for (int tt = 0; tt < 2; ++tt) {
        unsigned short* wp = tt ? (unsigned short*)&w1 : (unsigned short*)&w0;
#pragma unroll
        for (int r = 0; r < 4; ++r) {
          const int kp = base_row + krel0 + p * 32 + tt * 16 + quad * 4 + r;
          const int dd = kp - qp;
          const bool ok = (kp >= 0) && (kp < 8192) && (dd >= -128) && (dd <= 128);
          const float pv = ok ? __expf(st[tt][r] * 0.125f) : 0.f;
          lsum += pv;
          wp[r] = f2bf_bits(pv);
        }
      }
      *(ushort4*)&strip[l15 * 40 + quad * 4] = w0;
      *(ushort4*)&strip[l15 * 40 + 16 + quad * 4] = w1;
      const s16x8 pf = *(const s16x8*)&strip[l15 * 40 + quad * 8];
      int kc = base_row + krel0 + p * 32 + quad * 8;
      kc = min(max(kc, 0), 8184);  // clamped lanes multiply P==0
#pragma unroll
      for (int dt = 0; dt < 4; ++dt) {
        const s16x8 va = *(const s16x8*)(Vbase + (size_t)(dt * 16 + l15) * 8192 + kc);
        o[dt] = MFMA16(va, pf, o[dt]);
      }
    }

    lsum += __shfl_xor(lsum, 16, 64);
    lsum += __shfl_xor(lsum, 32, 64);
    const float rinv = 1.f / lsum;
    unsigned short* obase = O + (size_t)(b * 8192 + qp) * 1024 + h * 64;
#pragma unroll
    for (int dt = 0; dt < 4; ++dt) {
      ushort4 w;
      unsigned short* wp = (unsigned short*)&w;
#pragma unroll
      for (int r = 0; r < 4; ++r) wp[r] = f2bf_bits(o[dt][r] * rinv);
      *(ushort4*)(obase + dt * 16 + quad * 4) = w;
    }
  }
}

extern "C" void kernel_launch(void* const* d_in, const int* in_sizes, int n_in, void* d_out,
                              int out_size, void* d_ws, size_t ws_size, hipStream_t stream) {
  const float* x = (const float*)d_in[0];
  const float* Wq = (const float*)d_in[1];
  const float* bq = (const float*)d_in[2];
  const float* Wk = (const float*)d_in[3];
  const float* bk = (const float*)d_in[4];
  const float* Wv = (const float*)d_in[5];
  const float* bv = (const float*)d_in[6];
  const float* Wo = (const float*)d_in[7];
  const float* bo = (const float*)d_in[8];
  float* out = (float*)d_out;

  const int M = 16384, D = 1024;

  unsigned short* xb = (unsigned short*)d_ws;  // [16384,1024] bf16
  unsigned short* qb = xb + (size_t)M * D;     // [16384,1024]
  unsigned short* kb = qb + (size_t)M * D;     // [16384,1024]
  unsigned short* vt = kb + (size_t)M * D;     // [2048,8192] (V transposed)
  unsigned short* ab = vt + (size_t)M * D;     // [16384,1024] attention out
  unsigned short* wqb = ab + (size_t)M * D;    // weights bf16
  unsigned short* wkb = wqb + (size_t)D * D;
  unsigned short* wvb = wkb + (size_t)D * D;
  unsigned short* wob = wvb + (size_t)D * D;

  f2bf_kernel<<<16384, 256, 0, stream>>>(x, xb, M * D / 4);
  f2bf_w4<<<dim3(1024, 4), 256, 0, stream>>>(Wq, Wk, Wv, Wo, wqb, wkb, wvb, wob);

  gemm_qkv<<<dim3(M / 256, 12), 512, 0, stream>>>(xb, wqb, wkb, wvb, bq, bk, bv, qb, kb, vt);

  attn_kernel<<<dim3(64, 32), 256, 0, stream>>>(qb, kb, vt, ab);

  gemm_out<<<dim3(M / 256, D / 256), 512, 0, stream>>>(ab, wob, bo, out);
}